// Round 1
// baseline (291.260 us; speedup 1.0000x reference)
//
#include <hip/hip_runtime.h>

// DFMB PSROIAlign, position-sensitive ROI align.
// C=10 channels, 7x7 bins, 34x34 feature map, 4x4 subsamples, stride 8.
// Structure: one block = one bin (ph,pw) x 256 rois. The 10 feature planes
// for this bin (10 x 34 x 34 floats = 46.2 KB) are staged in LDS; each thread
// handles one roi, computing coords once and looping channels from LDS.

#define NC 10
#define PPH 7
#define PPW 7
#define FH 34
#define FW 34
#define NSUB 4
#define NBIN (PPH * PPW)
#define PLANE (FH * FW)

__global__ __launch_bounds__(256) void psroi_kernel(
    const float* __restrict__ ft, const float* __restrict__ rois,
    float* __restrict__ out, int N)
{
    __shared__ float sft[NC][PLANE];

    const int bin = blockIdx.x;          // 0..48
    const int ph  = bin / PPW;
    const int pw  = bin - ph * PPW;

    // Stage the 10 planes for this (ph,pw): plane c is at channel c*49+bin.
    const int base = bin * PLANE;
    for (int i = threadIdx.x; i < NC * PLANE; i += 256) {
        const int c = i / PLANE;
        const int p = i - c * PLANE;
        sft[c][p] = ft[(size_t)c * (NBIN * PLANE) + base + p];
    }
    __syncthreads();

    const int n = blockIdx.y * 256 + threadIdx.x;
    if (n >= N) return;

    // roi coords / STRIDE(8) — *0.125f is exact (power of two).
    const float rsw = rois[n * 5 + 1] * 0.125f;
    const float rsh = rois[n * 5 + 2] * 0.125f;
    const float rew = rois[n * 5 + 3] * 0.125f;
    const float reh = rois[n * 5 + 4] * 0.125f;

    // NOTE: coordinate chain uses explicit _rn intrinsics to forbid fp
    // contraction — floor/ceil/compare inputs must bit-match the numpy ref.
    float rheight = __fsub_rn(reh, rsh);
    if (!(rheight > 0.1f)) rheight = 0.1f;
    float rwidth = __fsub_rn(rew, rsw);
    if (!(rwidth > 0.1f)) rwidth = 0.1f;

    const float bsh   = __fdiv_rn(rheight, 7.0f);
    const float bsw   = __fdiv_rn(rwidth, 7.0f);
    const float sub_h = __fdiv_rn(bsh, 4.0f);
    const float sub_w = __fdiv_rn(bsw, 4.0f);

    const float hstart = floorf(__fadd_rn(rsh, __fmul_rn((float)ph, bsh)));
    const float wstart = floorf(__fadd_rn(rsw, __fmul_rn((float)pw, bsw)));

    float sum[NC];
#pragma unroll
    for (int c = 0; c < NC; ++c) sum[c] = 0.0f;
    float cnt = 0.0f;

#pragma unroll
    for (int ih = 0; ih < NSUB; ++ih) {
        const float h = __fadd_rn(hstart, __fmul_rn((float)ih + 0.5f, sub_h));
        const bool hok = (h > -1.0f) && (h < (float)FH);
        const int y1i = (int)floorf(h);
        const int y2i = (int)ceilf(h);
        const bool y1v = (y1i >= 0) && (y1i < FH);
        const bool y2v = (y2i >= 0) && (y2i < FH);
        const int y1c = min(max(y1i, 0), FH - 1);
        const int y2c = min(max(y2i, 0), FH - 1);
        const float dy = __fsub_rn(h, (float)y1c);  // dist vs CLIPPED corner (ref semantics)

#pragma unroll
        for (int iw = 0; iw < NSUB; ++iw) {
            const float w = __fadd_rn(wstart, __fmul_rn((float)iw + 0.5f, sub_w));
            if (!(hok && (w > -1.0f) && (w < (float)FW))) continue;  // keep==false: no sum, no count
            cnt += 1.0f;

            const int x1i = (int)floorf(w);
            const int x2i = (int)ceilf(w);
            const bool x1v = (x1i >= 0) && (x1i < FW);
            const bool x2v = (x2i >= 0) && (x2i < FW);
            const int x1c = min(max(x1i, 0), FW - 1);
            const int x2c = min(max(x2i, 0), FW - 1);
            const float dx = __fsub_rn(w, (float)x1c);

            const float w11 = (1.0f - dx) * (1.0f - dy);
            const float w12 = (1.0f - dx) * dy;
            const float w21 = dx * (1.0f - dy);
            const float w22 = dx * dy;

            // ref zeroes ONLY v11 when (x1 or x2 invalid) and (y1 or y2 valid)
            const bool bad11 = ((!x1v) || (!x2v)) && (y1v || y2v);

            const int i11 = y1c * FW + x1c;
            const int i12 = y2c * FW + x1c;
            const int i21 = y1c * FW + x2c;
            const int i22 = y2c * FW + x2c;

#pragma unroll
            for (int c = 0; c < NC; ++c) {
                const float v11 = bad11 ? 0.0f : sft[c][i11];
                const float v12 = sft[c][i12];
                const float v21 = sft[c][i21];
                const float v22 = sft[c][i22];
                sum[c] += w11 * v11 + w12 * v12 + w21 * v21 + w22 * v22;
            }
        }
    }

    // out[n, c, bin] = count>0 ? sum/count : sum (sum==0 when count==0)
    float* op = out + (size_t)n * (NC * NBIN) + bin;
    if (cnt > 0.0f) {
#pragma unroll
        for (int c = 0; c < NC; ++c) op[(size_t)c * NBIN] = __fdiv_rn(sum[c], cnt);
    } else {
#pragma unroll
        for (int c = 0; c < NC; ++c) op[(size_t)c * NBIN] = sum[c];
    }
}

extern "C" void kernel_launch(void* const* d_in, const int* in_sizes, int n_in,
                              void* d_out, int out_size, void* d_ws, size_t ws_size,
                              hipStream_t stream) {
    const float* ft   = (const float*)d_in[0];
    const float* rois = (const float*)d_in[1];
    float* out        = (float*)d_out;
    const int N = in_sizes[1] / 5;

    dim3 grid(NBIN, (N + 255) / 256);
    psroi_kernel<<<grid, dim3(256), 0, stream>>>(ft, rois, out, N);
}

// Round 2
// 201.401 us; speedup vs baseline: 1.4462x; 1.4462x over previous
//
#include <hip/hip_runtime.h>

// DFMB PSROIAlign. C=10, 7x7 bins, 34x34 map, 4x4 subsamples, stride 8.
// Kernel 1: block = one bin x 256 rois. LDS holds the 10 channel planes for
// this bin CHANNEL-INTERLEAVED: sft[pixel][c] padded to 12 floats (48B,
// 16B-aligned) so one bilinear corner's 10 channels = b128+b128+b64 LDS reads
// (3 instrs) instead of 10x ds_read_b32.
// Writes go to ws[(c*49+bin)*N + n] (lane-contiguous, coalesced) to avoid the
// 10x write-amplification of the strided out[n][c][bin] layout (R1 counters:
// WRITE_SIZE 570MB for 59MB of output). Kernel 2: tiled 64x64 transpose.

#define NC 10
#define PPH 7
#define PPW 7
#define FH 34
#define FW 34
#define NSUB 4
#define NBIN (PPH * PPW)
#define PLANE (FH * FW)
#define CPAD 12   // pad 10 channels to 12 floats = 48B, multiple of 16B

__global__ __launch_bounds__(256) void psroi_kernel(
    const float* __restrict__ ft, const float* __restrict__ rois,
    float* __restrict__ dst, int N, int direct)
{
    __shared__ __align__(16) float sft[PLANE * CPAD];  // 55.5 KB -> 2 blocks/CU

    const int bin = blockIdx.x;          // 0..48
    const int ph  = bin / PPW;
    const int pw  = bin - ph * PPW;
    const int base = bin * PLANE;

    // Stage interleaved: 10 coalesced global reads per pixel, 3 vector LDS writes.
    for (int p = threadIdx.x; p < PLANE; p += 256) {
        float v[NC];
#pragma unroll
        for (int c = 0; c < NC; ++c)
            v[c] = ft[(size_t)c * (NBIN * PLANE) + base + p];
        float4* d = reinterpret_cast<float4*>(&sft[p * CPAD]);
        d[0] = make_float4(v[0], v[1], v[2], v[3]);
        d[1] = make_float4(v[4], v[5], v[6], v[7]);
        d[2] = make_float4(v[8], v[9], 0.f, 0.f);
    }
    __syncthreads();

    const int n = blockIdx.y * 256 + threadIdx.x;
    if (n >= N) return;

    // roi coords / STRIDE(8) — *0.125f exact (pow2).
    const float rsw = rois[n * 5 + 1] * 0.125f;
    const float rsh = rois[n * 5 + 2] * 0.125f;
    const float rew = rois[n * 5 + 3] * 0.125f;
    const float reh = rois[n * 5 + 4] * 0.125f;

    // Explicit _rn chain: floor/ceil/compare inputs must bit-match numpy fp32.
    float rheight = __fsub_rn(reh, rsh);
    if (!(rheight > 0.1f)) rheight = 0.1f;
    float rwidth = __fsub_rn(rew, rsw);
    if (!(rwidth > 0.1f)) rwidth = 0.1f;

    const float bsh   = __fdiv_rn(rheight, 7.0f);
    const float bsw   = __fdiv_rn(rwidth, 7.0f);
    const float sub_h = __fdiv_rn(bsh, 4.0f);
    const float sub_w = __fdiv_rn(bsw, 4.0f);

    const float hstart = floorf(__fadd_rn(rsh, __fmul_rn((float)ph, bsh)));
    const float wstart = floorf(__fadd_rn(rsw, __fmul_rn((float)pw, bsw)));

    float sum[NC];
#pragma unroll
    for (int c = 0; c < NC; ++c) sum[c] = 0.0f;
    float cnt = 0.0f;

#pragma unroll
    for (int ih = 0; ih < NSUB; ++ih) {
        const float h = __fadd_rn(hstart, __fmul_rn((float)ih + 0.5f, sub_h));
        const bool hok = (h > -1.0f) && (h < (float)FH);
        const int y1i = (int)floorf(h);
        const int y2i = (int)ceilf(h);
        const bool y1v = (y1i >= 0) && (y1i < FH);
        const bool y2v = (y2i >= 0) && (y2i < FH);
        const int y1c = min(max(y1i, 0), FH - 1);
        const int y2c = min(max(y2i, 0), FH - 1);
        const float dy = __fsub_rn(h, (float)y1c);  // vs CLIPPED corner (ref semantics)

#pragma unroll
        for (int iw = 0; iw < NSUB; ++iw) {
            const float w = __fadd_rn(wstart, __fmul_rn((float)iw + 0.5f, sub_w));
            if (!(hok && (w > -1.0f) && (w < (float)FW))) continue;
            cnt += 1.0f;

            const int x1i = (int)floorf(w);
            const int x2i = (int)ceilf(w);
            const bool x1v = (x1i >= 0) && (x1i < FW);
            const bool x2v = (x2i >= 0) && (x2i < FW);
            const int x1c = min(max(x1i, 0), FW - 1);
            const int x2c = min(max(x2i, 0), FW - 1);
            const float dx = __fsub_rn(w, (float)x1c);

            float w11 = (1.0f - dx) * (1.0f - dy);
            const float w12 = (1.0f - dx) * dy;
            const float w21 = dx * (1.0f - dy);
            const float w22 = dx * dy;
            // ref zeroes ONLY v11 when (x1 or x2 invalid) and (y1 or y2 valid);
            // v11 enters only via w11, so zero the weight instead.
            if (((!x1v) || (!x2v)) && (y1v || y2v)) w11 = 0.0f;

            const int i11 = (y1c * FW + x1c) * CPAD;
            const int i12 = (y2c * FW + x1c) * CPAD;
            const int i21 = (y1c * FW + x2c) * CPAD;
            const int i22 = (y2c * FW + x2c) * CPAD;

            const float4 a11 = *(const float4*)&sft[i11];
            const float4 b11 = *(const float4*)&sft[i11 + 4];
            const float2 c11 = *(const float2*)&sft[i11 + 8];
            const float4 a12 = *(const float4*)&sft[i12];
            const float4 b12 = *(const float4*)&sft[i12 + 4];
            const float2 c12 = *(const float2*)&sft[i12 + 8];
            const float4 a21 = *(const float4*)&sft[i21];
            const float4 b21 = *(const float4*)&sft[i21 + 4];
            const float2 c21 = *(const float2*)&sft[i21 + 8];
            const float4 a22 = *(const float4*)&sft[i22];
            const float4 b22 = *(const float4*)&sft[i22 + 4];
            const float2 c22 = *(const float2*)&sft[i22 + 8];

            sum[0] += w11 * a11.x + w12 * a12.x + w21 * a21.x + w22 * a22.x;
            sum[1] += w11 * a11.y + w12 * a12.y + w21 * a21.y + w22 * a22.y;
            sum[2] += w11 * a11.z + w12 * a12.z + w21 * a21.z + w22 * a22.z;
            sum[3] += w11 * a11.w + w12 * a12.w + w21 * a21.w + w22 * a22.w;
            sum[4] += w11 * b11.x + w12 * b12.x + w21 * b21.x + w22 * b22.x;
            sum[5] += w11 * b11.y + w12 * b12.y + w21 * b21.y + w22 * b22.y;
            sum[6] += w11 * b11.z + w12 * b12.z + w21 * b21.z + w22 * b22.z;
            sum[7] += w11 * b11.w + w12 * b12.w + w21 * b21.w + w22 * b22.w;
            sum[8] += w11 * c11.x + w12 * c12.x + w21 * c21.x + w22 * c22.x;
            sum[9] += w11 * c11.y + w12 * c12.y + w21 * c21.y + w22 * c22.y;
        }
    }

    const float inv = (cnt > 0.0f) ? 1.0f : 0.0f;  // cnt==0 -> sums are 0, write as-is
    if (direct) {
        float* op = dst + (size_t)n * (NC * NBIN) + bin;
#pragma unroll
        for (int c = 0; c < NC; ++c)
            op[(size_t)c * NBIN] = (cnt > 0.0f) ? __fdiv_rn(sum[c], cnt) : sum[c];
    } else {
        // ws[(c*49+bin)*N + n]: lane-contiguous -> fully coalesced stores.
#pragma unroll
        for (int c = 0; c < NC; ++c)
            dst[(size_t)(c * NBIN + bin) * N + n] = (cnt > 0.0f) ? __fdiv_rn(sum[c], cnt) : sum[c];
    }
}

#define TD 64
__global__ __launch_bounds__(256) void transpose_kernel(
    const float* __restrict__ ws, float* __restrict__ out, int N)
{
    __shared__ float tile[TD][TD + 1];
    const int bc0 = blockIdx.x * TD;   // over 490
    const int n0  = blockIdx.y * TD;   // over N
    const int tl  = threadIdx.x % TD;
    const int tr  = threadIdx.x / TD;

#pragma unroll
    for (int r = tr; r < TD; r += 4) {
        const int bc = bc0 + r, n = n0 + tl;
        if (bc < NC * NBIN && n < N) tile[r][tl] = ws[(size_t)bc * N + n];
    }
    __syncthreads();
#pragma unroll
    for (int r = tr; r < TD; r += 4) {
        const int n = n0 + r, bc = bc0 + tl;
        if (n < N && bc < NC * NBIN) out[(size_t)n * (NC * NBIN) + bc] = tile[tl][r];
    }
}

extern "C" void kernel_launch(void* const* d_in, const int* in_sizes, int n_in,
                              void* d_out, int out_size, void* d_ws, size_t ws_size,
                              hipStream_t stream) {
    const float* ft   = (const float*)d_in[0];
    const float* rois = (const float*)d_in[1];
    float* out        = (float*)d_out;
    const int N = in_sizes[1] / 5;

    const size_t need = (size_t)NC * NBIN * N * sizeof(float);
    const int direct = (ws_size < need) ? 1 : 0;
    float* stage = direct ? out : (float*)d_ws;

    dim3 grid1(NBIN, (N + 255) / 256);
    psroi_kernel<<<grid1, dim3(256), 0, stream>>>(ft, rois, stage, N, direct);

    if (!direct) {
        dim3 grid2((NC * NBIN + TD - 1) / TD, (N + TD - 1) / TD);
        transpose_kernel<<<grid2, dim3(256), 0, stream>>>((const float*)d_ws, out, N);
    }
}

// Round 3
// 128.978 us; speedup vs baseline: 2.2582x; 1.5615x over previous
//
#include <hip/hip_runtime.h>

// DFMB PSROIAlign — separable (rank-1) weight formulation.
// Key fact: sub_w = bin_size_w/4 <= 0.322, so the 16 subsamples of one
// (roi,bin) span < 1px and all their bilinear corners live in a 3x3 pixel
// patch [Y0..Y0+2]x[X0..X0+2]. Bilinear weights, the keep gate
// (hok(ih)&wok(iw)) and the bad11 gate (badx(iw)&ybit(ih)) are separable, so
// the total per-pixel weight is W[p][q] = AY[p]*AX[q] - BY[p]*BX[q] and
// count = cntY*cntX. 9 gathers per (roi,bin) instead of 64.
//
// prep_kernel: transpose fm to ftT[bin][pixel][c(pad16)] (64B/pixel, 3.6MB,
// L2-resident) so one patch pixel's 10 channels = 2x b128 + 1x b64 load.
// main_kernel: block = 16 rois x 49 bins (16 slots/roi); results staged in a
// 16x491 LDS tile (odd stride) and flushed to out[n][490] fully coalesced —
// no workspace round-trip, no transpose kernel (R2: that cost ~30us + 118MB).

#define NC 10
#define NBIN 49
#define FH 34
#define FW 34
#define PLANE (FH * FW)
#define CSTRIDE 16   // floats per pixel in ftT (64B = one cacheline)
#define RPB 16       // rois per block
#define TSTRIDE 491  // LDS out-tile row stride (odd -> bank-conflict-free)

__global__ __launch_bounds__(256) void prep_kernel(
    const float* __restrict__ ft, float* __restrict__ ftT)
{
    const int p = blockIdx.x * 256 + threadIdx.x;  // over 49*1156 pixels
    if (p >= NBIN * PLANE) return;
    float v[NC];
#pragma unroll
    for (int c = 0; c < NC; ++c) v[c] = ft[c * (NBIN * PLANE) + p];
    float4* d = reinterpret_cast<float4*>(ftT + (size_t)p * CSTRIDE);
    d[0] = make_float4(v[0], v[1], v[2], v[3]);
    d[1] = make_float4(v[4], v[5], v[6], v[7]);
    d[2] = make_float4(v[8], v[9], 0.f, 0.f);
}

__global__ __launch_bounds__(256) void main_kernel(
    const float* __restrict__ rois, const float* __restrict__ ftT,
    const float* __restrict__ ft, float* __restrict__ out, int N, int use_t)
{
    __shared__ float tile[RPB][TSTRIDE];  // 31.4 KB -> ~5 blocks/CU

    const int r = threadIdx.x & (RPB - 1);  // roi within block
    const int s = threadIdx.x >> 4;         // slot 0..15
    const int n = blockIdx.x * RPB + r;
    const bool valid = (n < N);

    float rsw = 0.f, rsh = 0.f, rew = 0.f, reh = 0.f;
    if (valid) {
        rsw = rois[n * 5 + 1] * 0.125f;  // /STRIDE(8), exact pow2
        rsh = rois[n * 5 + 2] * 0.125f;
        rew = rois[n * 5 + 3] * 0.125f;
        reh = rois[n * 5 + 4] * 0.125f;
    }
    // Explicit _rn chain: floor/ceil/compare inputs must match numpy fp32.
    float rheight = __fsub_rn(reh, rsh);
    if (!(rheight > 0.1f)) rheight = 0.1f;
    float rwidth = __fsub_rn(rew, rsw);
    if (!(rwidth > 0.1f)) rwidth = 0.1f;
    const float bsh   = __fdiv_rn(rheight, 7.0f);
    const float bsw   = __fdiv_rn(rwidth, 7.0f);
    const float sub_h = __fdiv_rn(bsh, 4.0f);
    const float sub_w = __fdiv_rn(bsw, 4.0f);

#pragma unroll
    for (int j = 0; j < 4; ++j) {
        const int bin = j * 16 + s;
        if (valid && bin < NBIN) {
            const int ph = bin / 7;
            const int pw = bin - ph * 7;
            const float hstart = floorf(__fadd_rn(rsh, __fmul_rn((float)ph, bsh)));
            const float wstart = floorf(__fadd_rn(rsw, __fmul_rn((float)pw, bsw)));

            // ---- Y side: AY (bilinear), BY (bad11 correction), cntY ----
            float AY[3] = {0.f, 0.f, 0.f}, BY[3] = {0.f, 0.f, 0.f};
            float cntY = 0.f;
            int Y0 = 0;
#pragma unroll
            for (int ih = 0; ih < 4; ++ih) {
                const float h = __fadd_rn(hstart, __fmul_rn((float)ih + 0.5f, sub_h));
                const bool hok = (h > -1.0f) && (h < (float)FH);
                const int y1 = (int)floorf(h);
                const int y2 = (int)ceilf(h);
                const bool y1v = (y1 >= 0) && (y1 < FH);
                const bool y2v = (y2 >= 0) && (y2 < FH);
                const int y1c = min(max(y1, 0), FH - 1);
                const int y2c = min(max(y2, 0), FH - 1);
                const float dy = __fsub_rn(h, (float)y1c);  // vs CLIPPED corner
                if (ih == 0) Y0 = y1c;                      // min (h increasing)
                const int i1 = y1c - Y0, i2 = y2c - Y0;     // in {0,1,2}
                const float t1 = hok ? (1.0f - dy) : 0.0f;
                const float t2 = hok ? dy : 0.0f;
                const float tb = (hok && (y1v || y2v)) ? (1.0f - dy) : 0.0f;
                cntY += hok ? 1.0f : 0.0f;
#pragma unroll
                for (int p = 0; p < 3; ++p) {
                    AY[p] += (i1 == p) ? t1 : 0.0f;
                    AY[p] += (i2 == p) ? t2 : 0.0f;
                    BY[p] += (i1 == p) ? tb : 0.0f;
                }
            }

            // ---- X side ----
            float AX[3] = {0.f, 0.f, 0.f}, BX[3] = {0.f, 0.f, 0.f};
            float cntX = 0.f;
            int X0 = 0;
#pragma unroll
            for (int iw = 0; iw < 4; ++iw) {
                const float w = __fadd_rn(wstart, __fmul_rn((float)iw + 0.5f, sub_w));
                const bool wok = (w > -1.0f) && (w < (float)FW);
                const int x1 = (int)floorf(w);
                const int x2 = (int)ceilf(w);
                const bool x1v = (x1 >= 0) && (x1 < FW);
                const bool x2v = (x2 >= 0) && (x2 < FW);
                const int x1c = min(max(x1, 0), FW - 1);
                const int x2c = min(max(x2, 0), FW - 1);
                const float dx = __fsub_rn(w, (float)x1c);
                if (iw == 0) X0 = x1c;
                const int i1 = x1c - X0, i2 = x2c - X0;
                const float t1 = wok ? (1.0f - dx) : 0.0f;
                const float t2 = wok ? dx : 0.0f;
                // ref zeroes ONLY v11 when (x1 or x2 invalid) and (y1 or y2 valid)
                const float tb = (wok && ((!x1v) || (!x2v))) ? (1.0f - dx) : 0.0f;
                cntX += wok ? 1.0f : 0.0f;
#pragma unroll
                for (int q = 0; q < 3; ++q) {
                    AX[q] += (i1 == q) ? t1 : 0.0f;
                    AX[q] += (i2 == q) ? t2 : 0.0f;
                    BX[q] += (i1 == q) ? tb : 0.0f;
                }
            }

            // ---- 3x3 patch accumulation ----
            float sum[NC];
#pragma unroll
            for (int c = 0; c < NC; ++c) sum[c] = 0.f;

            const int binbase = bin * PLANE;
#pragma unroll
            for (int p = 0; p < 3; ++p) {
                const int py = min(Y0 + p, FH - 1);
#pragma unroll
                for (int q = 0; q < 3; ++q) {
                    const int px = min(X0 + q, FW - 1);
                    const float wgt = AY[p] * AX[q] - BY[p] * BX[q];
                    if (wgt != 0.0f) {  // exec-masks lanes -> saves L2 traffic
                        if (use_t) {
                            const float* pix = ftT + (size_t)(binbase + py * FW + px) * CSTRIDE;
                            const float4 a  = *(const float4*)pix;
                            const float4 b  = *(const float4*)(pix + 4);
                            const float2 c2 = *(const float2*)(pix + 8);
                            sum[0] += wgt * a.x;  sum[1] += wgt * a.y;
                            sum[2] += wgt * a.z;  sum[3] += wgt * a.w;
                            sum[4] += wgt * b.x;  sum[5] += wgt * b.y;
                            sum[6] += wgt * b.z;  sum[7] += wgt * b.w;
                            sum[8] += wgt * c2.x; sum[9] += wgt * c2.y;
                        } else {
                            const int off = binbase + py * FW + px;
#pragma unroll
                            for (int c = 0; c < NC; ++c)
                                sum[c] += wgt * ft[c * (NBIN * PLANE) + off];
                        }
                    }
                }
            }

            const float cnt = cntY * cntX;
            const float inv = (cnt > 0.0f) ? __fdiv_rn(1.0f, cnt) : 1.0f;
            float* tp = &tile[r][0];
#pragma unroll
            for (int c = 0; c < NC; ++c) tp[c * NBIN + bin] = sum[c] * inv;
        }
    }

    __syncthreads();

    // Coalesced flush: 16 rois x 490 contiguous floats each.
    const int n0 = blockIdx.x * RPB;
    for (int i = threadIdx.x; i < RPB * (NC * NBIN); i += 256) {
        const int row = i / (NC * NBIN);
        const int col = i - row * (NC * NBIN);
        const int n2 = n0 + row;
        if (n2 < N) out[(size_t)n2 * (NC * NBIN) + col] = tile[row][col];
    }
}

extern "C" void kernel_launch(void* const* d_in, const int* in_sizes, int n_in,
                              void* d_out, int out_size, void* d_ws, size_t ws_size,
                              hipStream_t stream) {
    const float* ft   = (const float*)d_in[0];
    const float* rois = (const float*)d_in[1];
    float* out        = (float*)d_out;
    const int N = in_sizes[1] / 5;

    const size_t need = (size_t)NBIN * PLANE * CSTRIDE * sizeof(float);  // 3.63 MB
    const int use_t = (ws_size >= need) ? 1 : 0;
    float* ftT = (float*)d_ws;

    if (use_t) {
        const int npix = NBIN * PLANE;
        prep_kernel<<<(npix + 255) / 256, 256, 0, stream>>>(ft, ftT);
    }
    main_kernel<<<(N + RPB - 1) / RPB, 256, 0, stream>>>(rois, ftT, ft, out, N, use_t);
}

// Round 4
// 125.785 us; speedup vs baseline: 2.3155x; 1.0254x over previous
//
#include <hip/hip_runtime.h>

// DFMB PSROIAlign — separable (rank-1) weights + phase-split side computation.
//
// Per (roi,bin) the 16 subsamples live in a 3x3 pixel patch; total per-pixel
// weight W[p][q] = AY[p]*AX[q] - BY[p]*BX[q], count = cntY*cntX (bilinear,
// keep-gate and bad11-gate are all separable in ih/iw).
//
// R3 lesson: each lane recomputed both sides per bin (98 side-computations per
// roi; only 14 are distinct) and gated patch loads behind per-pixel branches
// (9 serialized L2 latencies). Here:
//   phase 1: slot s<7 computes Y-side ph=s, s in 7..13 computes X-side pw=s-7
//            (FH==FW==34 lets one code path do both; only the bad11 predicate
//            differs: Y uses (y1v||y2v), X uses (!x1v||!x2v)). -> 7 KB LDS.
//   phase 2: read sides from LDS, form 9 weights, issue all 27 patch loads
//            BRANCH-FREE: wgt==0 pixels get address cndmask'd to plane pixel 0
//            (shared line, ~free) and contribute 0*garbage = 0.
// Output staged in a 16x491 LDS tile, flushed coalesced (no ws round-trip).

#define NC 10
#define NBIN 49
#define FH 34
#define FW 34
#define PLANE (FH * FW)
#define CSTRIDE 16   // floats per pixel in ftT (64B = one cache line)
#define RPB 16       // rois per block
#define TSTRIDE 491  // out-tile row stride (odd -> conflict-free flush)
#define NSIDE 14

__global__ __launch_bounds__(256) void prep_kernel(
    const float* __restrict__ ft, float* __restrict__ ftT)
{
    const int p = blockIdx.x * 256 + threadIdx.x;  // over 49*1156 pixels
    if (p >= NBIN * PLANE) return;
    float v[NC];
#pragma unroll
    for (int c = 0; c < NC; ++c) v[c] = ft[c * (NBIN * PLANE) + p];
    float4* d = reinterpret_cast<float4*>(ftT + (size_t)p * CSTRIDE);
    d[0] = make_float4(v[0], v[1], v[2], v[3]);
    d[1] = make_float4(v[4], v[5], v[6], v[7]);
    d[2] = make_float4(v[8], v[9], 0.f, 0.f);
}

__global__ __launch_bounds__(256) void main_kernel(
    const float* __restrict__ rois, const float* __restrict__ ftT,
    const float* __restrict__ ft, float* __restrict__ out, int N, int use_t)
{
    __shared__ float sides[NSIDE][RPB][8];  // 7 KB
    __shared__ float tile[RPB][TSTRIDE];    // 31.4 KB

    const int r = threadIdx.x & (RPB - 1);  // roi within block
    const int s = threadIdx.x >> 4;         // slot 0..15
    const int n = blockIdx.x * RPB + r;
    const bool valid = (n < N);

    float rsw = 0.f, rsh = 0.f, rew = 0.f, reh = 0.f;
    if (valid) {
        rsw = rois[n * 5 + 1] * 0.125f;  // /STRIDE(8), exact pow2
        rsh = rois[n * 5 + 2] * 0.125f;
        rew = rois[n * 5 + 3] * 0.125f;
        reh = rois[n * 5 + 4] * 0.125f;
    }
    // Explicit _rn chain: floor/ceil/compare inputs must bit-match numpy fp32.
    float rheight = __fsub_rn(reh, rsh);
    if (!(rheight > 0.1f)) rheight = 0.1f;
    float rwidth = __fsub_rn(rew, rsw);
    if (!(rwidth > 0.1f)) rwidth = 0.1f;
    const float bsh   = __fdiv_rn(rheight, 7.0f);
    const float bsw   = __fdiv_rn(rwidth, 7.0f);
    const float sub_h = __fdiv_rn(bsh, 4.0f);
    const float sub_w = __fdiv_rn(bsw, 4.0f);

    // ---- phase 1: one axis-side per slot (14 of 16 slots active) ----
    if (s < NSIDE) {
        const bool isY = (s < 7);
        const int  k   = isY ? s : s - 7;
        const float st = isY ? rsh : rsw;
        const float bs = isY ? bsh : bsw;
        const float sb = isY ? sub_h : sub_w;
        const float start = floorf(__fadd_rn(st, __fmul_rn((float)k, bs)));

        float A[3] = {0.f, 0.f, 0.f}, B[3] = {0.f, 0.f, 0.f};
        float cnt = 0.f;
        int P0 = 0;
#pragma unroll
        for (int i = 0; i < 4; ++i) {
            const float h = __fadd_rn(start, __fmul_rn((float)i + 0.5f, sb));
            const bool ok = (h > -1.0f) && (h < 34.0f);
            const int p1 = (int)floorf(h);
            const int p2 = (int)ceilf(h);
            const bool v1 = (p1 >= 0) && (p1 < 34);
            const bool v2 = (p2 >= 0) && (p2 < 34);
            const int p1c = min(max(p1, 0), 33);
            const int p2c = min(max(p2, 0), 33);
            const float d = __fsub_rn(h, (float)p1c);  // vs CLIPPED corner
            if (i == 0) P0 = p1c;                      // min (h increasing)
            const int i1 = p1c - P0, i2 = p2c - P0;    // in {0,1,2}
            const float t1 = ok ? (1.0f - d) : 0.0f;
            const float t2 = ok ? d : 0.0f;
            // bad11 = (!x1v || !x2v) && (y1v || y2v): X carries the "invalid"
            // factor, Y the "valid" factor.
            const bool bsel = isY ? (v1 || v2) : ((!v1) || (!v2));
            const float tb = (ok && bsel) ? (1.0f - d) : 0.0f;
            cnt += ok ? 1.0f : 0.0f;
#pragma unroll
            for (int p = 0; p < 3; ++p) {
                A[p] += (i1 == p) ? t1 : 0.0f;
                A[p] += (i2 == p) ? t2 : 0.0f;
                B[p] += (i1 == p) ? tb : 0.0f;
            }
        }
        float* sp = &sides[s][r][0];
        sp[0] = A[0]; sp[1] = A[1]; sp[2] = A[2];
        sp[3] = B[0]; sp[4] = B[1]; sp[5] = B[2];
        sp[6] = cnt;  sp[7] = (float)P0;
    }
    __syncthreads();

    // ---- phase 2: 4 bins per thread, branch-free batched patch loads ----
#pragma unroll
    for (int j = 0; j < 4; ++j) {
        const int bin = j * RPB + s;
        if (valid && bin < NBIN) {
            const int ph = bin / 7;
            const int pw = bin - ph * 7;

            const float4 ya = *(const float4*)&sides[ph][r][0];
            const float4 yb = *(const float4*)&sides[ph][r][4];
            const float4 xa = *(const float4*)&sides[7 + pw][r][0];
            const float4 xb = *(const float4*)&sides[7 + pw][r][4];
            const float AY[3] = {ya.x, ya.y, ya.z};
            const float BY[3] = {ya.w, yb.x, yb.y};
            const float cntY  = yb.z;
            const int   Y0    = (int)yb.w;
            const float AX[3] = {xa.x, xa.y, xa.z};
            const float BX[3] = {xa.w, xb.x, xb.y};
            const float cntX  = xb.z;
            const int   X0    = (int)xb.w;

            const int binbase = bin * PLANE;
            const int rowo[3] = {binbase + Y0 * FW,
                                 binbase + min(Y0 + 1, FH - 1) * FW,
                                 binbase + min(Y0 + 2, FH - 1) * FW};
            const int colo[3] = {X0, min(X0 + 1, FW - 1), min(X0 + 2, FW - 1)};

            float wgt[9];
            int   off[9];
#pragma unroll
            for (int p = 0; p < 3; ++p)
#pragma unroll
                for (int q = 0; q < 3; ++q) {
                    const float w = AY[p] * AX[q] - BY[p] * BX[q];
                    wgt[3 * p + q] = w;
                    // zero-weight -> shared dummy pixel (plane origin): loads
                    // stay batched, masked lanes share one hot line.
                    off[3 * p + q] = (w != 0.0f) ? (rowo[p] + colo[q]) : binbase;
                }

            float sum[NC];
#pragma unroll
            for (int c = 0; c < NC; ++c) sum[c] = 0.f;

            if (use_t) {
#pragma unroll
                for (int k = 0; k < 9; ++k) {
                    const float* pix = ftT + (size_t)off[k] * CSTRIDE;
                    const float4 a  = *(const float4*)pix;
                    const float4 b  = *(const float4*)(pix + 4);
                    const float2 c2 = *(const float2*)(pix + 8);
                    const float w = wgt[k];
                    sum[0] = fmaf(w, a.x, sum[0]);
                    sum[1] = fmaf(w, a.y, sum[1]);
                    sum[2] = fmaf(w, a.z, sum[2]);
                    sum[3] = fmaf(w, a.w, sum[3]);
                    sum[4] = fmaf(w, b.x, sum[4]);
                    sum[5] = fmaf(w, b.y, sum[5]);
                    sum[6] = fmaf(w, b.z, sum[6]);
                    sum[7] = fmaf(w, b.w, sum[7]);
                    sum[8] = fmaf(w, c2.x, sum[8]);
                    sum[9] = fmaf(w, c2.y, sum[9]);
                }
            } else {
#pragma unroll
                for (int k = 0; k < 9; ++k) {
                    const float w = wgt[k];
#pragma unroll
                    for (int c = 0; c < NC; ++c)
                        sum[c] = fmaf(w, ft[c * (NBIN * PLANE) + off[k]], sum[c]);
                }
            }

            const float cnt = cntY * cntX;
            const float inv = (cnt > 0.0f) ? __fdiv_rn(1.0f, cnt) : 1.0f;
            float* tp = &tile[r][0];
#pragma unroll
            for (int c = 0; c < NC; ++c) tp[c * NBIN + bin] = sum[c] * inv;
        }
    }

    __syncthreads();

    // Coalesced flush: 16 rois x 490 contiguous floats each.
    const int n0 = blockIdx.x * RPB;
    for (int i = threadIdx.x; i < RPB * (NC * NBIN); i += 256) {
        const int row = i / (NC * NBIN);
        const int col = i - row * (NC * NBIN);
        const int n2 = n0 + row;
        if (n2 < N) out[(size_t)n2 * (NC * NBIN) + col] = tile[row][col];
    }
}

extern "C" void kernel_launch(void* const* d_in, const int* in_sizes, int n_in,
                              void* d_out, int out_size, void* d_ws, size_t ws_size,
                              hipStream_t stream) {
    const float* ft   = (const float*)d_in[0];
    const float* rois = (const float*)d_in[1];
    float* out        = (float*)d_out;
    const int N = in_sizes[1] / 5;

    const size_t need = (size_t)NBIN * PLANE * CSTRIDE * sizeof(float);  // 3.63 MB
    const int use_t = (ws_size >= need) ? 1 : 0;
    float* ftT = (float*)d_ws;

    if (use_t) {
        const int npix = NBIN * PLANE;
        prep_kernel<<<(npix + 255) / 256, 256, 0, stream>>>(ft, ftT);
    }
    main_kernel<<<(N + RPB - 1) / RPB, 256, 0, stream>>>(rois, ftT, ft, out, N, use_t);
}